// Round 16
// baseline (264.259 us; speedup 1.0000x reference)
//
#include <hip/hip_runtime.h>

#define Bb 16
#define Lq 2048
#define Dd 64
#define QT 16          // q-rows per block
#define NT 512         // 8 waves, wave w = ks owns 16 k-rows/window
#define NWIN 16        // 16 windows of 128 k-rows
#define WINB 32768     // 32 KB per K window (128 rows x 256 B)

typedef _Float16 f16x2 __attribute__((ext_vector_type(2)));
typedef _Float16 f16x8 __attribute__((ext_vector_type(8)));
typedef __attribute__((ext_vector_type(4))) float f32x4;
typedef __attribute__((ext_vector_type(2))) float f32x2;
typedef __attribute__((ext_vector_type(4))) unsigned int u32x4;
typedef __attribute__((ext_vector_type(2))) unsigned int u32x2;
typedef __attribute__((ext_vector_type(4))) int i32x4;
typedef unsigned long long u64;

union H8 { f16x8 v8; f16x2 h2[4]; unsigned int u[4]; u32x4 u4; };
union H1 { f16x2 h; unsigned int u; };

__device__ __forceinline__ f16x2 pkrtz(float a, float b) {
  return __builtin_bit_cast(f16x2, __builtin_amdgcn_cvt_pkrtz(a, b));
}
__device__ __forceinline__ f32x4 MF16(f16x8 a, f16x8 b, f32x4 c) {
  return __builtin_amdgcn_mfma_f32_16x16x32_f16(a, b, c, 0, 0, 0);
}
__device__ __forceinline__ f32x4 MFu(u32x4 a, const H8& b, f32x4 c) {
  return MF16(__builtin_bit_cast(f16x8, a), b.v8, c);
}
__device__ __forceinline__ void gl_lds16(const void* g, void* l) {
  __builtin_amdgcn_global_load_lds(
      (const __attribute__((address_space(1))) void*)g,
      (__attribute__((address_space(3))) void*)l, 16, 0, 0);
}

// ---- prep: K -> h/l 32KB windows slot-swizzled; V -> window-pair B-frag order
__global__ __launch_bounds__(256)
void sdpa_prep(const float* __restrict__ kg, const float* __restrict__ vg,
               u32x4* __restrict__ Kw4, u32x4* __restrict__ Vq)
{
  const int t = threadIdx.x, blk = blockIdx.x;
  if (blk < 1024) {                        // K: 32 rows/block, 8 octets/row
    const int row = blk * 32 + (t >> 3);
    const int oct = t & 7;
    const int b = row >> 11, r = row & 2047;
    const int win = r >> 7, rw = r & 127;
    const float* kp = kg + (size_t)row * Dd + oct * 8;
    f32x4 a = *(const f32x4*)kp;
    f32x4 c = *(const f32x4*)(kp + 4);
    H1 h0, h1, h2, h3, l0, l1, l2, l3;
    h0.h = pkrtz(a.x, a.y); l0.h = pkrtz(a.x - (float)h0.h.x, a.y - (float)h0.h.y);
    h1.h = pkrtz(a.z, a.w); l1.h = pkrtz(a.z - (float)h1.h.x, a.w - (float)h1.h.y);
    h2.h = pkrtz(c.x, c.y); l2.h = pkrtz(c.x - (float)h2.h.x, c.y - (float)h2.h.y);
    h3.h = pkrtz(c.z, c.w); l3.h = pkrtz(c.z - (float)h3.h.x, c.w - (float)h3.h.y);
    u32x4 hh = {h0.u, h1.u, h2.u, h3.u};
    u32x4 ll = {l0.u, l1.u, l2.u, l3.u};
    const int sl = oct ^ (rw & 7);
    const size_t base = ((size_t)((b * 16 + win) * 128 + rw)) * 16;
    Kw4[base + sl] = hh;
    Kw4[base + 8 + sl] = ll;
  } else {                                 // V: window-pair B-frags
    const int v_ = (blk - 1024) * 256 + t;
    const int ln = v_ & 15, nt = (v_ >> 4) & 3, u = (v_ >> 6) & 3;
    const int ks = (v_ >> 8) & 7, g = (v_ >> 11) & 7, b = v_ >> 14;
    const int r0 = g * 256 + ks * 16 + 4 * u;
    const float* vp = vg + ((size_t)b * Lq + r0) * Dd + nt * 16 + ln;
    H1 p0, p1, p2, p3;
    p0.h = pkrtz(vp[0],        vp[64]);
    p1.h = pkrtz(vp[128],      vp[192]);
    p2.h = pkrtz(vp[128 * 64], vp[129 * 64]);
    p3.h = pkrtz(vp[130 * 64], vp[131 * 64]);
    u32x4 o = {p0.u, p1.u, p2.u, p3.u};
    Vq[v_] = o;
  }
}

// ---------------------------- main kernel ----------------------------
// R13 dbuf structure + mask stream folded INTO the loop (1-pair lookahead).
// LDS: kbuf 64K + Q 4.6K + mb2 1.3K + red 0.6K = ~70.5 KB -> 2 blocks/CU.
__global__ __launch_bounds__(NT, 4)
void sdpa_main(const float* __restrict__ qg, const char* __restrict__ Kw,
               const u32x4* __restrict__ Vqp, const i32x4* __restrict__ mg4,
               float* __restrict__ outO, float* __restrict__ outA)
{
  __shared__ alignas(16) char kbuf[2][WINB];      // 64 KB K-window dbuf
  __shared__ unsigned int Qh[QT][36], Ql[QT][36]; // 4.6 KB
  __shared__ u64 mb2[2][QT][5];                   // mask bitplanes, pair dbuf
  __shared__ float red[QT][8];
  __shared__ float dinv_s[QT];

  const int tid = threadIdx.x;
  const int l   = tid & 63;
  const int ln  = l & 15;
  const int u   = l >> 4;
  const int w   = tid >> 6;        // 0..7 = ks
  const int bid = (int)(blockIdx.x % 8) * 256 + (int)(blockIdx.x / 8); // XCD swz
  const int b   = bid >> 7;
  const int q0  = (bid & 127) * QT;
  const int ks  = w;

  // Phase 0: Q (16 rows) -> f16 h/l split planes in LDS
  {
    int r = tid >> 5, d2 = tid & 31;
    f32x2 qv = *(const f32x2*)(qg + (size_t)(b * Lq + q0 + r) * Dd + 2 * d2);
    H1 h, lo;
    h.h  = pkrtz(qv.x, qv.y);
    lo.h = pkrtz(qv.x - (float)h.h.x, qv.y - (float)h.h.y);
    Qh[r][d2] = h.u;
    Ql[r][d2] = lo.u;
  }

  const char* kwb = Kw + (size_t)b * NWIN * WINB;
  auto STAGE = [&](int buf_, int win_) {
#pragma unroll
    for (int i = 0; i < 4; ++i)
      gl_lds16(kwb + (size_t)win_ * WINB + i * 8192 + w * 1024 + l * 16,
               &kbuf[buf_][i * 8192 + w * 1024]);
  };
  // mask pack for one pair g_: wave w covers rows 2w, 2w+1; 8 ballots
  auto MPACK = [&](int g_) {
#pragma unroll
    for (int i = 0; i < 2; ++i) {
      const int row = 2 * w + i;
      i32x4 mm = __builtin_nontemporal_load(
          &mg4[(size_t)(b * Lq + q0 + row) * 512 + g_ * 64 + l]);
      u64 b0 = __ballot(mm.x != 0);
      u64 b1 = __ballot(mm.y != 0);
      u64 b2 = __ballot(mm.z != 0);
      u64 b3 = __ballot(mm.w != 0);
      if (l < 4) mb2[g_ & 1][row][l] = (l == 0) ? b0 : (l == 1) ? b1 : (l == 2) ? b2 : b3;
    }
  };

  STAGE(0, 0);
  MPACK(0);
  __syncthreads();   // Q planes + mb2[0] visible + window-0 DMA drained

  H8 Bh0, Bh1, Bl0, Bl1;
  Bh0.u4 = *(const u32x4*)&Qh[ln][4 * u];
  Bh1.u4 = *(const u32x4*)&Qh[ln][16 + 4 * u];
  Bl0.u4 = *(const u32x4*)&Ql[ln][4 * u];
  Bl1.u4 = *(const u32x4*)&Ql[ln][16 + 4 * u];

  unsigned int su[NWIN][2];
  f32x4 pv[4] = {{0,0,0,0},{0,0,0,0},{0,0,0,0},{0,0,0,0}};
  float rs = 0.f;
  const int key = ln & 7;
  const int sh  = ks * 4 + u;
  u32x4 MA = {0,0,0,0}, MC = {0,0,0,0};
  u32x4 vbuf[4];

  // ---- fused window loop (dbuf DMA; mask stream interleaved, 1-pair ahead) --
#pragma unroll
  for (int win = 0; win < NWIN; ++win) {
    const int cur = win & 1;
    if (win < NWIN - 1) STAGE(cur ^ 1, win + 1);

    if ((win & 1) == 0) {
      const int g = win >> 1;
      const u64* mr = &mb2[g & 1][ln][0];         // this pair's bits (ready)
      MA = *(const u32x4*)mr;
      MC = *(const u32x4*)(mr + 2);
      const u32x4* vq = Vqp + (size_t)b * 16384 + (((g * 8 + ks) * 4 + u) * 4) * 16 + ln;
#pragma unroll
      for (int nt = 0; nt < 4; ++nt) vbuf[nt] = vq[nt * 16];
      if (g < 7) MPACK(g + 1);                    // stream next pair's mask
    }
    unsigned mw0 = (win & 1) ? MA.y : MA.x;
    unsigned mw1 = (win & 1) ? MA.w : MA.z;
    unsigned mw2 = (win & 1) ? MC.y : MC.x;
    unsigned mw3 = (win & 1) ? MC.w : MC.z;

    // QK^T on current window (rows ks*16+ln), 6 MFMA
    {
      const int rw = ks * 16 + ln;
      const char* rp = &kbuf[cur][0] + rw * 256;
      u32x4 h0  = *(const u32x4*)(rp + ((u ^ key) << 4));
      u32x4 h1  = *(const u32x4*)(rp + (((4 + u) ^ key) << 4));
      u32x4 l0_ = *(const u32x4*)(rp + ((8 | (u ^ key)) << 4));
      u32x4 l1_ = *(const u32x4*)(rp + ((8 | ((4 + u) ^ key)) << 4));
      f32x4 acc = {0.f, 0.f, 0.f, 0.f};
      acc = MFu(h0, Bh0, acc);
      acc = MFu(h0, Bl0, acc);
      acc = MFu(l0_, Bh0, acc);
      acc = MFu(h1, Bh1, acc);
      acc = MFu(h1, Bl1, acc);
      acc = MFu(l1_, Bh1, acc);
      float s0 = ((mw0 >> sh) & 1u) ? 0.f : acc.x;
      float s1 = ((mw1 >> sh) & 1u) ? 0.f : acc.y;
      float s2 = ((mw2 >> sh) & 1u) ? 0.f : acc.z;
      float s3 = ((mw3 >> sh) & 1u) ? 0.f : acc.w;
      rs += (s0 + s1) + (s2 + s3);
      H1 p0, p1;
      p0.h = pkrtz(s0, s1); p1.h = pkrtz(s2, s3);
      su[win][0] = p0.u; su[win][1] = p1.u;
    }
    // PV per window-pair
    if (win & 1) {
      H8 aw;
      aw.u[0] = su[win - 1][0]; aw.u[1] = su[win - 1][1];
      aw.u[2] = su[win][0];     aw.u[3] = su[win][1];
      pv[0] = MF16(aw.v8, __builtin_bit_cast(f16x8, vbuf[0]), pv[0]);
      pv[1] = MF16(aw.v8, __builtin_bit_cast(f16x8, vbuf[1]), pv[1]);
      pv[2] = MF16(aw.v8, __builtin_bit_cast(f16x8, vbuf[2]), pv[2]);
      pv[3] = MF16(aw.v8, __builtin_bit_cast(f16x8, vbuf[3]), pv[3]);
    }
    __syncthreads();   // win+1 DMA drained; mb2 writes visible; buffers rotate
  }

  // ---- row-sums -> dinv ----
  rs += __shfl_xor(rs, 16);
  rs += __shfl_xor(rs, 32);
  if (l < 16) red[l][ks] = rs;
  // S -> LDS transpose buffer (kbuf alias, 64 KB), XOR-swizzled 8B units
  {
    char* srow = &kbuf[0][0] + ln * 4096;
    const unsigned skey = (unsigned)ln << 3;
#pragma unroll
    for (int win = 0; win < NWIN; ++win) {
      unsigned Bo = 256u * win + 32u * ks + 8u * u;
      u32x2 pk2 = {su[win][0], su[win][1]};
      *(u32x2*)(srow + (Bo ^ skey)) = pk2;
    }
  }
  __syncthreads();
  if (tid < QT) {
    f32x4 r0 = *(const f32x4*)&red[tid][0];
    f32x4 r1 = *(const f32x4*)&red[tid][4];
    float s = ((r0.x + r0.y) + (r0.z + r0.w)) + ((r1.x + r1.y) + (r1.z + r1.w));
    dinv_s[tid] = 1.0f / fmaxf(s, 1e-14f);
  }
  __syncthreads();

  // ---- attn stores: 2 rows/wave, 1KB-contiguous nontemporal bursts ----
  {
    const char* Sb = &kbuf[0][0];
#pragma unroll
    for (int r = 0; r < 2; ++r) {
      const int rr = 2 * w + r;
      const float dv = dinv_s[rr];
      const char* sr = Sb + rr * 4096;
      const unsigned rk = (unsigned)rr << 3;
      float* arow = outA + (size_t)(b * Lq + q0 + rr) * Lq;
#pragma unroll
      for (int m = 0; m < 8; ++m) {
        u32x2 pk = *(const u32x2*)(sr + ((unsigned)(512 * m + 8 * l) ^ rk));
        H1 a0, a1; a0.u = pk.x; a1.u = pk.y;
        f32x4 st = {(float)a0.h.x * dv, (float)a0.h.y * dv,
                    (float)a1.h.x * dv, (float)a1.h.y * dv};
        __builtin_nontemporal_store(st, (f32x4*)(arow + 256 * m + 4 * l));
      }
    }
  }
  __syncthreads();                 // all Sb reads done -> Or may alias

  // ---- cross-ks O reduction (kbuf alias) + store ----
  {
    float (*Or)[16][66] = (float (*)[16][66])&kbuf[0][0];   // [8][16][66]
#pragma unroll
    for (int nt = 0; nt < 4; ++nt)
#pragma unroll
      for (int r2 = 0; r2 < 4; ++r2)
        Or[ks][4 * u + r2][16 * nt + ln] = pv[nt][r2];
    __syncthreads();
    {
      int q_ = tid >> 5, d = (tid & 31) * 2;
      float o0 = 0.f, o1 = 0.f;
#pragma unroll
      for (int k2 = 0; k2 < 8; ++k2) {
        o0 += Or[k2][q_][d];
        o1 += Or[k2][q_][d + 1];
      }
      float dvq = dinv_s[q_];
      f32x2 st = {o0 * dvq, o1 * dvq};
      *(f32x2*)(outO + (size_t)(b * Lq + q0 + q_) * Dd + d) = st;
    }
  }
}

extern "C" void kernel_launch(void* const* d_in, const int* in_sizes, int n_in,
                              void* d_out, int out_size, void* d_ws, size_t ws_size,
                              hipStream_t stream) {
  const float* q = (const float*)d_in[0];
  const float* k = (const float*)d_in[1];
  const float* v = (const float*)d_in[2];
  const int*   m = (const int*)d_in[3];
  float* outO = (float*)d_out;
  float* outA = outO + (size_t)Bb * Lq * Dd;

  char* ws = (char*)d_ws;
  u32x4* Kw4 = (u32x4*)ws;                    // 8 MB swizzled K h/l windows
  u32x4* Vq  = (u32x4*)(ws + (8u << 20));     // 4 MB V window-pair B-frags
  sdpa_prep<<<2048, 256, 0, stream>>>(k, v, Kw4, Vq);
  sdpa_main<<<Bb * (Lq / QT), NT, 0, stream>>>(q, (const char*)Kw4, Vq,
                                               (const i32x4*)m, outO, outA);
}

// Round 17
// 222.618 us; speedup vs baseline: 1.1871x; 1.1871x over previous
//
#include <hip/hip_runtime.h>

#define Bb 16
#define Lq 2048
#define Dd 64
#define QT 16          // q-rows per block
#define NT 512         // 8 waves, wave w = ks owns 16 k-rows/window
#define NWIN 16        // 16 windows of 128 k-rows
#define WINB 32768     // 32 KB per K window (128 rows x 256 B)

typedef _Float16 f16x2 __attribute__((ext_vector_type(2)));
typedef _Float16 f16x8 __attribute__((ext_vector_type(8)));
typedef __attribute__((ext_vector_type(4))) float f32x4;
typedef __attribute__((ext_vector_type(2))) float f32x2;
typedef __attribute__((ext_vector_type(4))) unsigned int u32x4;
typedef __attribute__((ext_vector_type(2))) unsigned int u32x2;
typedef __attribute__((ext_vector_type(4))) int i32x4;
typedef unsigned long long u64;

union H8 { f16x8 v8; f16x2 h2[4]; unsigned int u[4]; u32x4 u4; };
union H1 { f16x2 h; unsigned int u; };

__device__ __forceinline__ f16x2 pkrtz(float a, float b) {
  return __builtin_bit_cast(f16x2, __builtin_amdgcn_cvt_pkrtz(a, b));
}
__device__ __forceinline__ f32x4 MF16(f16x8 a, f16x8 b, f32x4 c) {
  return __builtin_amdgcn_mfma_f32_16x16x32_f16(a, b, c, 0, 0, 0);
}
__device__ __forceinline__ f32x4 MFu(u32x4 a, const H8& b, f32x4 c) {
  return MF16(__builtin_bit_cast(f16x8, a), b.v8, c);
}
__device__ __forceinline__ void gl_lds16(const void* g, void* l) {
  __builtin_amdgcn_global_load_lds(
      (const __attribute__((address_space(1))) void*)g,
      (__attribute__((address_space(3))) void*)l, 16, 0, 0);
}

// ---- prep: K -> h/l 32KB windows slot-swizzled; V -> window-pair B-frag order
__global__ __launch_bounds__(256)
void sdpa_prep(const float* __restrict__ kg, const float* __restrict__ vg,
               u32x4* __restrict__ Kw4, u32x4* __restrict__ Vq)
{
  const int t = threadIdx.x, blk = blockIdx.x;
  if (blk < 1024) {                        // K: 32 rows/block, 8 octets/row
    const int row = blk * 32 + (t >> 3);
    const int oct = t & 7;
    const int b = row >> 11, r = row & 2047;
    const int win = r >> 7, rw = r & 127;
    const float* kp = kg + (size_t)row * Dd + oct * 8;
    f32x4 a = *(const f32x4*)kp;
    f32x4 c = *(const f32x4*)(kp + 4);
    H1 h0, h1, h2, h3, l0, l1, l2, l3;
    h0.h = pkrtz(a.x, a.y); l0.h = pkrtz(a.x - (float)h0.h.x, a.y - (float)h0.h.y);
    h1.h = pkrtz(a.z, a.w); l1.h = pkrtz(a.z - (float)h1.h.x, a.w - (float)h1.h.y);
    h2.h = pkrtz(c.x, c.y); l2.h = pkrtz(c.x - (float)h2.h.x, c.y - (float)h2.h.y);
    h3.h = pkrtz(c.z, c.w); l3.h = pkrtz(c.z - (float)h3.h.x, c.w - (float)h3.h.y);
    u32x4 hh = {h0.u, h1.u, h2.u, h3.u};
    u32x4 ll = {l0.u, l1.u, l2.u, l3.u};
    const int sl = oct ^ (rw & 7);
    const size_t base = ((size_t)((b * 16 + win) * 128 + rw)) * 16;
    Kw4[base + sl] = hh;
    Kw4[base + 8 + sl] = ll;
  } else {                                 // V: window-pair B-frags
    const int v_ = (blk - 1024) * 256 + t;
    const int ln = v_ & 15, nt = (v_ >> 4) & 3, u = (v_ >> 6) & 3;
    const int ks = (v_ >> 8) & 7, g = (v_ >> 11) & 7, b = v_ >> 14;
    const int r0 = g * 256 + ks * 16 + 4 * u;
    const float* vp = vg + ((size_t)b * Lq + r0) * Dd + nt * 16 + ln;
    H1 p0, p1, p2, p3;
    p0.h = pkrtz(vp[0],        vp[64]);
    p1.h = pkrtz(vp[128],      vp[192]);
    p2.h = pkrtz(vp[128 * 64], vp[129 * 64]);
    p3.h = pkrtz(vp[130 * 64], vp[131 * 64]);
    u32x4 o = {p0.u, p1.u, p2.u, p3.u};
    Vq[v_] = o;
  }
}

// ---------------------------- main kernel ----------------------------
// R16 structure; register-pressure fixes: bounds (512,2) + mask words read
// per-window from LDS (no cross-window mask registers).
// LDS: kbuf 64K + Q 4.6K + mb2 1.3K + red 0.6K = ~72 KB -> 2 blocks/CU.
__global__ __launch_bounds__(NT, 2)
void sdpa_main(const float* __restrict__ qg, const char* __restrict__ Kw,
               const u32x4* __restrict__ Vqp, const i32x4* __restrict__ mg4,
               float* __restrict__ outO, float* __restrict__ outA)
{
  __shared__ alignas(16) char kbuf[2][WINB];      // 64 KB K-window dbuf
  __shared__ unsigned int Qh[QT][36], Ql[QT][36]; // 4.6 KB
  __shared__ u64 mb2[2][QT][5];                   // mask bitplanes, pair dbuf
  __shared__ float red[QT][8];
  __shared__ float dinv_s[QT];

  const int tid = threadIdx.x;
  const int l   = tid & 63;
  const int ln  = l & 15;
  const int u   = l >> 4;
  const int w   = tid >> 6;        // 0..7 = ks
  const int bid = (int)(blockIdx.x % 8) * 256 + (int)(blockIdx.x / 8); // XCD swz
  const int b   = bid >> 7;
  const int q0  = (bid & 127) * QT;
  const int ks  = w;

  // Phase 0: Q (16 rows) -> f16 h/l split planes in LDS
  {
    int r = tid >> 5, d2 = tid & 31;
    f32x2 qv = *(const f32x2*)(qg + (size_t)(b * Lq + q0 + r) * Dd + 2 * d2);
    H1 h, lo;
    h.h  = pkrtz(qv.x, qv.y);
    lo.h = pkrtz(qv.x - (float)h.h.x, qv.y - (float)h.h.y);
    Qh[r][d2] = h.u;
    Ql[r][d2] = lo.u;
  }

  const char* kwb = Kw + (size_t)b * NWIN * WINB;
  auto STAGE = [&](int buf_, int win_) {
#pragma unroll
    for (int i = 0; i < 4; ++i)
      gl_lds16(kwb + (size_t)win_ * WINB + i * 8192 + w * 1024 + l * 16,
               &kbuf[buf_][i * 8192 + w * 1024]);
  };
  // mask pack for one pair g_: wave w covers rows 2w, 2w+1; 8 ballots
  auto MPACK = [&](int g_) {
#pragma unroll
    for (int i = 0; i < 2; ++i) {
      const int row = 2 * w + i;
      i32x4 mm = __builtin_nontemporal_load(
          &mg4[(size_t)(b * Lq + q0 + row) * 512 + g_ * 64 + l]);
      u64 b0 = __ballot(mm.x != 0);
      u64 b1 = __ballot(mm.y != 0);
      u64 b2 = __ballot(mm.z != 0);
      u64 b3 = __ballot(mm.w != 0);
      if (l < 4) mb2[g_ & 1][row][l] = (l == 0) ? b0 : (l == 1) ? b1 : (l == 2) ? b2 : b3;
    }
  };

  STAGE(0, 0);
  MPACK(0);
  __syncthreads();   // Q planes + mb2[0] visible + window-0 DMA drained

  H8 Bh0, Bh1, Bl0, Bl1;
  Bh0.u4 = *(const u32x4*)&Qh[ln][4 * u];
  Bh1.u4 = *(const u32x4*)&Qh[ln][16 + 4 * u];
  Bl0.u4 = *(const u32x4*)&Ql[ln][4 * u];
  Bl1.u4 = *(const u32x4*)&Ql[ln][16 + 4 * u];

  unsigned int su[NWIN][2];
  f32x4 pv[4] = {{0,0,0,0},{0,0,0,0},{0,0,0,0},{0,0,0,0}};
  float rs = 0.f;
  const int key = ln & 7;
  const int sh  = ks * 4 + u;
  u32x4 vbuf[4];

  // ---- fused window loop (dbuf DMA; mask stream interleaved, 1-pair ahead) --
#pragma unroll
  for (int win = 0; win < NWIN; ++win) {
    const int cur = win & 1;
    const int g   = win >> 1;
    const int p   = win & 1;
    if (win < NWIN - 1) STAGE(cur ^ 1, win + 1);

    if (p == 0) {
      const u32x4* vq = Vqp + (size_t)b * 16384 + (((g * 8 + ks) * 4 + u) * 4) * 16 + ln;
#pragma unroll
      for (int nt = 0; nt < 4; ++nt) vbuf[nt] = vq[nt * 16];
      if (g < 7) MPACK(g + 1);                    // stream next pair's mask
    }
    // mask words straight from LDS (broadcast across u; no register liveness)
    const unsigned* mw32 = (const unsigned*)&mb2[g & 1][ln][0];
    unsigned mw0 = mw32[0 + p];
    unsigned mw1 = mw32[2 + p];
    unsigned mw2 = mw32[4 + p];
    unsigned mw3 = mw32[6 + p];

    // QK^T on current window (rows ks*16+ln), 6 MFMA
    {
      const int rw = ks * 16 + ln;
      const char* rp = &kbuf[cur][0] + rw * 256;
      u32x4 h0  = *(const u32x4*)(rp + ((u ^ key) << 4));
      u32x4 h1  = *(const u32x4*)(rp + (((4 + u) ^ key) << 4));
      u32x4 l0_ = *(const u32x4*)(rp + ((8 | (u ^ key)) << 4));
      u32x4 l1_ = *(const u32x4*)(rp + ((8 | ((4 + u) ^ key)) << 4));
      f32x4 acc = {0.f, 0.f, 0.f, 0.f};
      acc = MFu(h0, Bh0, acc);
      acc = MFu(h0, Bl0, acc);
      acc = MFu(l0_, Bh0, acc);
      acc = MFu(h1, Bh1, acc);
      acc = MFu(h1, Bl1, acc);
      acc = MFu(l1_, Bh1, acc);
      float s0 = ((mw0 >> sh) & 1u) ? 0.f : acc.x;
      float s1 = ((mw1 >> sh) & 1u) ? 0.f : acc.y;
      float s2 = ((mw2 >> sh) & 1u) ? 0.f : acc.z;
      float s3 = ((mw3 >> sh) & 1u) ? 0.f : acc.w;
      rs += (s0 + s1) + (s2 + s3);
      H1 p0, p1;
      p0.h = pkrtz(s0, s1); p1.h = pkrtz(s2, s3);
      su[win][0] = p0.u; su[win][1] = p1.u;
    }
    // PV per window-pair
    if (p) {
      H8 aw;
      aw.u[0] = su[win - 1][0]; aw.u[1] = su[win - 1][1];
      aw.u[2] = su[win][0];     aw.u[3] = su[win][1];
      pv[0] = MF16(aw.v8, __builtin_bit_cast(f16x8, vbuf[0]), pv[0]);
      pv[1] = MF16(aw.v8, __builtin_bit_cast(f16x8, vbuf[1]), pv[1]);
      pv[2] = MF16(aw.v8, __builtin_bit_cast(f16x8, vbuf[2]), pv[2]);
      pv[3] = MF16(aw.v8, __builtin_bit_cast(f16x8, vbuf[3]), pv[3]);
    }
    __syncthreads();   // win+1 DMA drained; mb2 writes visible; buffers rotate
  }

  // ---- row-sums -> dinv ----
  rs += __shfl_xor(rs, 16);
  rs += __shfl_xor(rs, 32);
  if (l < 16) red[l][ks] = rs;
  // S -> LDS transpose buffer (kbuf alias, 64 KB), XOR-swizzled 8B units
  {
    char* srow = &kbuf[0][0] + ln * 4096;
    const unsigned skey = (unsigned)ln << 3;
#pragma unroll
    for (int win = 0; win < NWIN; ++win) {
      unsigned Bo = 256u * win + 32u * ks + 8u * u;
      u32x2 pk2 = {su[win][0], su[win][1]};
      *(u32x2*)(srow + (Bo ^ skey)) = pk2;
    }
  }
  __syncthreads();
  if (tid < QT) {
    f32x4 r0 = *(const f32x4*)&red[tid][0];
    f32x4 r1 = *(const f32x4*)&red[tid][4];
    float s = ((r0.x + r0.y) + (r0.z + r0.w)) + ((r1.x + r1.y) + (r1.z + r1.w));
    dinv_s[tid] = 1.0f / fmaxf(s, 1e-14f);
  }
  __syncthreads();

  // ---- attn stores: 2 rows/wave, 1KB-contiguous nontemporal bursts ----
  {
    const char* Sb = &kbuf[0][0];
#pragma unroll
    for (int r = 0; r < 2; ++r) {
      const int rr = 2 * w + r;
      const float dv = dinv_s[rr];
      const char* sr = Sb + rr * 4096;
      const unsigned rk = (unsigned)rr << 3;
      float* arow = outA + (size_t)(b * Lq + q0 + rr) * Lq;
#pragma unroll
      for (int m = 0; m < 8; ++m) {
        u32x2 pk = *(const u32x2*)(sr + ((unsigned)(512 * m + 8 * l) ^ rk));
        H1 a0, a1; a0.u = pk.x; a1.u = pk.y;
        f32x4 st = {(float)a0.h.x * dv, (float)a0.h.y * dv,
                    (float)a1.h.x * dv, (float)a1.h.y * dv};
        __builtin_nontemporal_store(st, (f32x4*)(arow + 256 * m + 4 * l));
      }
    }
  }
  __syncthreads();                 // all Sb reads done -> Or may alias

  // ---- cross-ks O reduction (kbuf alias) + store ----
  {
    float (*Or)[16][66] = (float (*)[16][66])&kbuf[0][0];   // [8][16][66]
#pragma unroll
    for (int nt = 0; nt < 4; ++nt)
#pragma unroll
      for (int r2 = 0; r2 < 4; ++r2)
        Or[ks][4 * u + r2][16 * nt + ln] = pv[nt][r2];
    __syncthreads();
    {
      int q_ = tid >> 5, d = (tid & 31) * 2;
      float o0 = 0.f, o1 = 0.f;
#pragma unroll
      for (int k2 = 0; k2 < 8; ++k2) {
        o0 += Or[k2][q_][d];
        o1 += Or[k2][q_][d + 1];
      }
      float dvq = dinv_s[q_];
      f32x2 st = {o0 * dvq, o1 * dvq};
      *(f32x2*)(outO + (size_t)(b * Lq + q0 + q_) * Dd + d) = st;
    }
  }
}

extern "C" void kernel_launch(void* const* d_in, const int* in_sizes, int n_in,
                              void* d_out, int out_size, void* d_ws, size_t ws_size,
                              hipStream_t stream) {
  const float* q = (const float*)d_in[0];
  const float* k = (const float*)d_in[1];
  const float* v = (const float*)d_in[2];
  const int*   m = (const int*)d_in[3];
  float* outO = (float*)d_out;
  float* outA = outO + (size_t)Bb * Lq * Dd;

  char* ws = (char*)d_ws;
  u32x4* Kw4 = (u32x4*)ws;                    // 8 MB swizzled K h/l windows
  u32x4* Vq  = (u32x4*)(ws + (8u << 20));     // 4 MB V window-pair B-frags
  sdpa_prep<<<2048, 256, 0, stream>>>(k, v, Kw4, Vq);
  sdpa_main<<<Bb * (Lq / QT), NT, 0, stream>>>(q, (const char*)Kw4, Vq,
                                               (const i32x4*)m, outO, outA);
}

// Round 18
// 159.868 us; speedup vs baseline: 1.6530x; 1.3925x over previous
//
#include <hip/hip_runtime.h>

#define Bb 16
#define Lq 2048
#define Dd 64
#define QT 16          // q-rows per block
#define NT 512         // 8 waves, wave w = ks owns 16 k-rows/window
#define NWIN 16        // 16 windows of 128 k-rows
#define WINB 32768     // 32 KB K window (128 rows x 256 B)

typedef _Float16 f16x2 __attribute__((ext_vector_type(2)));
typedef _Float16 f16x8 __attribute__((ext_vector_type(8)));
typedef __attribute__((ext_vector_type(4))) float f32x4;
typedef __attribute__((ext_vector_type(2))) float f32x2;
typedef __attribute__((ext_vector_type(4))) unsigned int u32x4;
typedef __attribute__((ext_vector_type(2))) unsigned int u32x2;
typedef __attribute__((ext_vector_type(4))) int i32x4;
typedef unsigned long long u64;

union H8 { f16x8 v8; f16x2 h2[4]; unsigned int u[4]; u32x4 u4; };
union H1 { f16x2 h; unsigned int u; };

__device__ __forceinline__ f16x2 pkrtz(float a, float b) {
  return __builtin_bit_cast(f16x2, __builtin_amdgcn_cvt_pkrtz(a, b));
}
__device__ __forceinline__ f32x4 MF16(f16x8 a, f16x8 b, f32x4 c) {
  return __builtin_amdgcn_mfma_f32_16x16x32_f16(a, b, c, 0, 0, 0);
}
__device__ __forceinline__ f32x4 MFu(u32x4 a, const H8& b, f32x4 c) {
  return MF16(__builtin_bit_cast(f16x8, a), b.v8, c);
}
__device__ __forceinline__ void gl_lds16(const void* g, void* l) {
  __builtin_amdgcn_global_load_lds(
      (const __attribute__((address_space(1))) void*)g,
      (__attribute__((address_space(3))) void*)l, 16, 0, 0);
}

// ---- prep: K -> h/l 32KB windows slot-swizzled; V -> window-pair B-frag order
__global__ __launch_bounds__(256)
void sdpa_prep(const float* __restrict__ kg, const float* __restrict__ vg,
               u32x4* __restrict__ Kw4, u32x4* __restrict__ Vq)
{
  const int t = threadIdx.x, blk = blockIdx.x;
  if (blk < 1024) {                        // K: 32 rows/block, 8 octets/row
    const int row = blk * 32 + (t >> 3);
    const int oct = t & 7;
    const int b = row >> 11, r = row & 2047;
    const int win = r >> 7, rw = r & 127;
    const float* kp = kg + (size_t)row * Dd + oct * 8;
    f32x4 a = *(const f32x4*)kp;
    f32x4 c = *(const f32x4*)(kp + 4);
    H1 h0, h1, h2, h3, l0, l1, l2, l3;
    h0.h = pkrtz(a.x, a.y); l0.h = pkrtz(a.x - (float)h0.h.x, a.y - (float)h0.h.y);
    h1.h = pkrtz(a.z, a.w); l1.h = pkrtz(a.z - (float)h1.h.x, a.w - (float)h1.h.y);
    h2.h = pkrtz(c.x, c.y); l2.h = pkrtz(c.x - (float)h2.h.x, c.y - (float)h2.h.y);
    h3.h = pkrtz(c.z, c.w); l3.h = pkrtz(c.z - (float)h3.h.x, c.w - (float)h3.h.y);
    u32x4 hh = {h0.u, h1.u, h2.u, h3.u};
    u32x4 ll = {l0.u, l1.u, l2.u, l3.u};
    const int sl = oct ^ (rw & 7);
    const size_t base = ((size_t)((b * 16 + win) * 128 + rw)) * 16;
    Kw4[base + sl] = hh;
    Kw4[base + 8 + sl] = ll;
  } else {                                 // V: window-pair B-frags
    const int v_ = (blk - 1024) * 256 + t;
    const int ln = v_ & 15, nt = (v_ >> 4) & 3, u = (v_ >> 6) & 3;
    const int ks = (v_ >> 8) & 7, g = (v_ >> 11) & 7, b = v_ >> 14;
    const int r0 = g * 256 + ks * 16 + 4 * u;
    const float* vp = vg + ((size_t)b * Lq + r0) * Dd + nt * 16 + ln;
    H1 p0, p1, p2, p3;
    p0.h = pkrtz(vp[0],        vp[64]);
    p1.h = pkrtz(vp[128],      vp[192]);
    p2.h = pkrtz(vp[128 * 64], vp[129 * 64]);
    p3.h = pkrtz(vp[130 * 64], vp[131 * 64]);
    u32x4 o = {p0.u, p1.u, p2.u, p3.u};
    Vq[v_] = o;
  }
}

// ---------------------------- main kernel ----------------------------
// LDS: kbuf 33.8K + Q/mask union 4.6K + red/dinv 0.6K = ~39 KB.
// __launch_bounds__(512,4): VGPR cap 64 (R13-proven, no spill).
__global__ __launch_bounds__(NT, 4)
void sdpa_main(const float* __restrict__ qg, const char* __restrict__ Kw,
               const u32x4* __restrict__ Vqp, const i32x4* __restrict__ mg4,
               float* __restrict__ outO, float* __restrict__ outA)
{
  __shared__ alignas(16) char kbuf[33792];        // K window / S half / Or
  __shared__ alignas(16) char qmbuf[4624];        // Q planes, later mask bits
  __shared__ float red[QT][8];
  __shared__ float dinv_s[QT];

  unsigned int (*Qh)[36] = (unsigned int (*)[36])qmbuf;
  unsigned int (*Ql)[36] = (unsigned int (*)[36])(qmbuf + 2304);
  u64 (*mbits)[34]       = (u64 (*)[34])qmbuf;

  const int tid = threadIdx.x;
  const int l   = tid & 63;
  const int ln  = l & 15;
  const int u   = l >> 4;
  const int w   = tid >> 6;        // 0..7 = ks
  const int bid = (int)(blockIdx.x % 8) * 256 + (int)(blockIdx.x / 8); // XCD swz
  const int b   = bid >> 7;
  const int q0  = (bid & 127) * QT;
  const int ks  = w;

  // Phase 0: Q (16 rows) -> f16 h/l split planes in LDS
  {
    int r = tid >> 5, d2 = tid & 31;
    f32x2 qv = *(const f32x2*)(qg + (size_t)(b * Lq + q0 + r) * Dd + 2 * d2);
    H1 h, lo;
    h.h  = pkrtz(qv.x, qv.y);
    lo.h = pkrtz(qv.x - (float)h.h.x, qv.y - (float)h.h.y);
    Qh[r][d2] = h.u;
    Ql[r][d2] = lo.u;
  }

  const char* kwb = Kw + (size_t)b * NWIN * WINB;
  auto STAGE = [&](int win_) {
#pragma unroll
    for (int i = 0; i < 4; ++i)
      gl_lds16(kwb + (size_t)win_ * WINB + i * 8192 + w * 1024 + l * 16,
               &kbuf[i * 8192 + w * 1024]);
  };
  STAGE(0);
  __syncthreads();                 // Q planes visible + window-0 DMA drained

  H8 Bh0, Bh1, Bl0, Bl1;
  Bh0.u4 = *(const u32x4*)&Qh[ln][4 * u];
  Bh1.u4 = *(const u32x4*)&Qh[ln][16 + 4 * u];
  Bl0.u4 = *(const u32x4*)&Ql[ln][4 * u];
  Bl1.u4 = *(const u32x4*)&Ql[ln][16 + 4 * u];
  __syncthreads();                 // B-frag reads done before mask overwrite

  // Phase 0b: per-block mask pack (own 16 rows, 128 KB coalesced)
#pragma unroll
  for (int i = 0; i < 2; ++i) {
    const int row = 2 * w + i;
    const size_t rbase = (size_t)(b * Lq + q0 + row) * 512;
#pragma unroll
    for (int W = 0; W < 8; ++W) {
      i32x4 mm = __builtin_nontemporal_load(&mg4[rbase + W * 64 + l]);
      u64 b0 = __ballot(mm.x != 0);
      u64 b1 = __ballot(mm.y != 0);
      u64 b2 = __ballot(mm.z != 0);
      u64 b3 = __ballot(mm.w != 0);
      if (l < 4) mbits[row][W * 4 + l] = (l == 0) ? b0 : (l == 1) ? b1 : (l == 2) ? b2 : b3;
    }
  }
  __syncthreads();

  unsigned int su[NWIN][2];
  f32x4 pv[4] = {{0,0,0,0},{0,0,0,0},{0,0,0,0},{0,0,0,0}};
  float rs = 0.f;
  const int key = ln & 7;
  const int sh  = ks * 4 + u;
  u32x4 MA = {0,0,0,0}, MC = {0,0,0,0};
  u32x4 vbuf[4];

  // ---- window loop, single K buffer: compute -> sync -> STAGE -> sync ----
#pragma unroll
  for (int win = 0; win < NWIN; ++win) {
    if ((win & 1) == 0) {
      const int g = win >> 1;
      const u64* mr = &mbits[ln][g * 4];
      MA = *(const u32x4*)mr;
      MC = *(const u32x4*)(mr + 2);
      const u32x4* vq = Vqp + (size_t)b * 16384 + (((g * 8 + ks) * 4 + u) * 4) * 16 + ln;
#pragma unroll
      for (int nt = 0; nt < 4; ++nt) vbuf[nt] = vq[nt * 16];
    }
    unsigned mw0 = (win & 1) ? MA.y : MA.x;
    unsigned mw1 = (win & 1) ? MA.w : MA.z;
    unsigned mw2 = (win & 1) ? MC.y : MC.x;
    unsigned mw3 = (win & 1) ? MC.w : MC.z;

    // QK^T on current window (rows ks*16+ln), 6 MFMA
    {
      const int rw = ks * 16 + ln;
      const char* rp = &kbuf[0] + rw * 256;
      u32x4 h0  = *(const u32x4*)(rp + ((u ^ key) << 4));
      u32x4 h1  = *(const u32x4*)(rp + (((4 + u) ^ key) << 4));
      u32x4 l0_ = *(const u32x4*)(rp + ((8 | (u ^ key)) << 4));
      u32x4 l1_ = *(const u32x4*)(rp + ((8 | ((4 + u) ^ key)) << 4));
      f32x4 acc = {0.f, 0.f, 0.f, 0.f};
      acc = MFu(h0, Bh0, acc);
      acc = MFu(h0, Bl0, acc);
      acc = MFu(l0_, Bh0, acc);
      acc = MFu(h1, Bh1, acc);
      acc = MFu(h1, Bl1, acc);
      acc = MFu(l1_, Bh1, acc);
      float s0 = ((mw0 >> sh) & 1u) ? 0.f : acc.x;
      float s1 = ((mw1 >> sh) & 1u) ? 0.f : acc.y;
      float s2 = ((mw2 >> sh) & 1u) ? 0.f : acc.z;
      float s3 = ((mw3 >> sh) & 1u) ? 0.f : acc.w;
      rs += (s0 + s1) + (s2 + s3);
      H1 p0, p1;
      p0.h = pkrtz(s0, s1); p1.h = pkrtz(s2, s3);
      su[win][0] = p0.u; su[win][1] = p1.u;
    }
    // PV per window-pair
    if (win & 1) {
      H8 aw;
      aw.u[0] = su[win - 1][0]; aw.u[1] = su[win - 1][1];
      aw.u[2] = su[win][0];     aw.u[3] = su[win][1];
      pv[0] = MF16(aw.v8, __builtin_bit_cast(f16x8, vbuf[0]), pv[0]);
      pv[1] = MF16(aw.v8, __builtin_bit_cast(f16x8, vbuf[1]), pv[1]);
      pv[2] = MF16(aw.v8, __builtin_bit_cast(f16x8, vbuf[2]), pv[2]);
      pv[3] = MF16(aw.v8, __builtin_bit_cast(f16x8, vbuf[3]), pv[3]);
    }
    __syncthreads();               // all waves done reading this window
    if (win < NWIN - 1) {
      STAGE(win + 1);
      __syncthreads();             // DMA drained -> window win+1 ready
    }
  }

  // ---- row-sums -> dinv ----
  rs += __shfl_xor(rs, 16);
  rs += __shfl_xor(rs, 32);
  if (l < 16) red[l][ks] = rs;
  __syncthreads();
  if (tid < QT) {
    f32x4 r0 = *(const f32x4*)&red[tid][0];
    f32x4 r1 = *(const f32x4*)&red[tid][4];
    float s = ((r0.x + r0.y) + (r0.z + r0.w)) + ((r1.x + r1.y) + (r1.z + r1.w));
    dinv_s[tid] = 1.0f / fmaxf(s, 1e-14f);
  }
  __syncthreads();

  // ---- attn stores in two 8-row halves via S-transpose in kbuf (32 KB) ----
#pragma unroll
  for (int half = 0; half < 2; ++half) {
    // writers: lanes whose q-row ln is in this half
    if ((ln >> 3) == half) {
      char* srow = &kbuf[0] + (ln & 7) * 4096;
      const unsigned skey = (unsigned)ln << 3;
#pragma unroll
      for (int win = 0; win < NWIN; ++win) {
        unsigned Bo = 256u * win + 32u * ks + 8u * u;
        u32x2 pk2 = {su[win][0], su[win][1]};
        *(u32x2*)(srow + (Bo ^ skey)) = pk2;
      }
    }
    __syncthreads();
    // all 8 waves store: 1 row/wave, 1KB-contiguous nontemporal bursts
    {
      const int rr = 8 * half + w;
      const float dv = dinv_s[rr];
      const char* sr = &kbuf[0] + w * 4096;
      const unsigned rk = (unsigned)rr << 3;
      float* arow = outA + (size_t)(b * Lq + q0 + rr) * Lq;
#pragma unroll
      for (int m = 0; m < 8; ++m) {
        u32x2 pk = *(const u32x2*)(sr + ((unsigned)(512 * m + 8 * l) ^ rk));
        H1 a0, a1; a0.u = pk.x; a1.u = pk.y;
        f32x4 st = {(float)a0.h.x * dv, (float)a0.h.y * dv,
                    (float)a1.h.x * dv, (float)a1.h.y * dv};
        __builtin_nontemporal_store(st, (f32x4*)(arow + 256 * m + 4 * l));
      }
    }
    __syncthreads();               // Sb reads done -> next half / Or may alias
  }

  // ---- cross-ks O reduction (kbuf alias, 33792 B exactly) + store ----
  {
    float (*Or)[16][66] = (float (*)[16][66])&kbuf[0];   // [8][16][66]
#pragma unroll
    for (int nt = 0; nt < 4; ++nt)
#pragma unroll
      for (int r2 = 0; r2 < 4; ++r2)
        Or[ks][4 * u + r2][16 * nt + ln] = pv[nt][r2];
    __syncthreads();
    {
      int q_ = tid >> 5, d = (tid & 31) * 2;
      float o0 = 0.f, o1 = 0.f;
#pragma unroll
      for (int k2 = 0; k2 < 8; ++k2) {
        o0 += Or[k2][q_][d];
        o1 += Or[k2][q_][d + 1];
      }
      float dvq = dinv_s[q_];
      f32x2 st = {o0 * dvq, o1 * dvq};
      *(f32x2*)(outO + (size_t)(b * Lq + q0 + q_) * Dd + d) = st;
    }
  }
}

extern "C" void kernel_launch(void* const* d_in, const int* in_sizes, int n_in,
                              void* d_out, int out_size, void* d_ws, size_t ws_size,
                              hipStream_t stream) {
  const float* q = (const float*)d_in[0];
  const float* k = (const float*)d_in[1];
  const float* v = (const float*)d_in[2];
  const int*   m = (const int*)d_in[3];
  float* outO = (float*)d_out;
  float* outA = outO + (size_t)Bb * Lq * Dd;

  char* ws = (char*)d_ws;
  u32x4* Kw4 = (u32x4*)ws;                    // 8 MB swizzled K h/l windows
  u32x4* Vq  = (u32x4*)(ws + (8u << 20));     // 4 MB V window-pair B-frags
  sdpa_prep<<<2048, 256, 0, stream>>>(k, v, Kw4, Vq);
  sdpa_main<<<Bb * (Lq / QT), NT, 0, stream>>>(q, (const char*)Kw4, Vq,
                                               (const i32x4*)m, outO, outA);
}